// Round 1
// 900.886 us; speedup vs baseline: 1.1356x; 1.1356x over previous
//
#include <hip/hip_runtime.h>
#include <hip/hip_bf16.h>
#include <stdint.h>

// ---------------------------------------------------------------------------
// GCN: h1 = relu(adj @ (x @ W1) + b1); h2 = relu(adj @ (h1 @ W2) + b2)
//      out[b] = (sum_{n<len[b]} h2[b,n,:] / len[b]) @ Wl + bl
// B=64, N=1024, NFEAT=512, NHID1=1024, NHID2=512
//
// R2: GEMMs ported from the 128^2/BK=32/2-barrier structure (m97-class,
//     ~625 TF measured, MfmaUtil 26%) to the 256^2/BK=64/8-wave 8-phase
//     template (T3+T4 counted vmcnt, T2 LDS XOR-swizzle via pre-swizzled
//     global source, T5 setprio). Pipeline: per tile t the 4 phases stage
//     {A-h1(t+1), B-h1(t+1), B-h0(t+2), A-h0(t+2)}; vmcnt(4) once per
//     K-tile (never 0 in the main loop). Tail prefetches wrap modulo NT
//     into the dead buffer (harmless).
// ---------------------------------------------------------------------------

typedef short bf16x8 __attribute__((ext_vector_type(8)));
typedef short s16x4 __attribute__((ext_vector_type(4)));
typedef float f32x4 __attribute__((ext_vector_type(4)));

__device__ __forceinline__ unsigned short f2bf(float f) {
    union { float f; unsigned u; } v; v.f = f;
    unsigned r = v.u + 0x7fffu + ((v.u >> 16) & 1u);   // RNE
    return (unsigned short)(r >> 16);
}
__device__ __forceinline__ float bf2f(unsigned short h) {
    union { unsigned u; float f; } v; v.u = ((unsigned)h) << 16;
    return v.f;
}

typedef const __attribute__((address_space(1))) void* gp1_t;
typedef __attribute__((address_space(3))) void* lp3_t;

__device__ __forceinline__ void ldsload16(const void* g, void* l) {
    // dest = wave-uniform LDS base + lane*16 (HW semantics)
    __builtin_amdgcn_global_load_lds((gp1_t)(uintptr_t)g,
                                     (lp3_t)(unsigned)(uintptr_t)l,
                                     16, 0, 0);
}

// raw barrier + zero-cost compiler memory fence (pins LDS/VMEM ops to phases)
#define BARF()   do { __builtin_amdgcn_s_barrier(); asm volatile("" ::: "memory"); } while (0)
#define LGKM0()  asm volatile("s_waitcnt lgkmcnt(0)" ::: "memory")
#define VMCNT4() asm volatile("s_waitcnt vmcnt(4)" ::: "memory")
#define MFMA16(d, a, b) d = __builtin_amdgcn_mfma_f32_16x16x32_bf16(a, b, d, 0, 0, 0)

// NT GEMM: C = A(MxK,row) * Bt(NxK,row)^T, bf16 in/out, fp32 accumulate.
// 256x256 tile, BK=64, 8 waves (2M x 4N), per-wave 128x64 output.
// SPLIT:  C index (m, nf) -> nf=b*1024+n stored at b*splitStride + m*1024 + n
// !SPLIT: C index (m, n)  -> z*cStride + m*N + n, optional bias[n] + relu
template<bool BIASRELU, bool SPLIT>
__global__ __launch_bounds__(512, 1)
void gemm_nt8(const short* __restrict__ A, const short* __restrict__ B,
              short* __restrict__ C, const float* __restrict__ bias,
              int M, int N, int K,
              long long aStride, long long bStride, long long cStride,
              long long splitStride)
{
    // [buf][A/B][256 rows][64 cols] bf16 = 128 KiB total
    __shared__ short sm[2][2][256 * 64];

    const int tid  = threadIdx.x;
    const int wid  = tid >> 6;        // 0..7
    const int lane = tid & 63;
    const int wm   = wid >> 2;        // 0..1 -> 128-row half
    const int wn   = wid & 3;         // 0..3 -> 64-col quarter
    const int quad = lane >> 4;       // 0..3
    const int l16  = lane & 15;

    const int bM = blockIdx.y * 256;
    const int bN = blockIdx.x * 256;
    const int z  = blockIdx.z;
    A += (long long)z * aStride;
    B += (long long)z * bStride;

    // --- staging addresses: thread t covers row (t>>3) of each 64-row chunk,
    //     16B at XOR-swizzled source column (rule 21: linear LDS dest,
    //     inverse-swizzled global source, swizzle applied again on ds_read)
    const int srow = tid >> 3;                                  // 0..63
    const int scbs = ((tid & 7) * 16) ^ ((srow & 7) << 4);      // swizzled col-byte
    const short* Ag = A + (long long)(bM + srow) * K + (scbs >> 1);
    const short* Bg = B + (long long)(bN + srow) * K + (scbs >> 1);
    const long long row64  = 64LL * K;
    const long long row128 = 128LL * K;

    // issue the two global_load_lds of one 128x64 half-tile (2 vmcnt events)
    #define STAGE(buf, ab, h, kt) do {                                        \
        const short* g_ = (ab ? Bg : Ag) + (h ? row128 : 0) + (kt) * 64;      \
        char* l_ = (char*)&sm[buf][ab][0] + (h) * 16384 + wid * 1024;         \
        ldsload16(g_, l_);                                                    \
        ldsload16(g_ + row64, l_ + 8192);                                     \
    } while (0)

    // swizzled ds_read column-bytes (row&7 == l16&7 for all fragment rows)
    const int cbs0 = (quad * 16) ^ ((l16 & 7) << 4);            // kk=0
    const int cbs1 = (64 + quad * 16) ^ ((l16 & 7) << 4);       // kk=1

    #define RDA(buf, m, kk) (*(const bf16x8*)((const char*)&sm[buf][0][0]     \
        + (wm * 128 + (m) * 16 + l16) * 128 + ((kk) ? cbs1 : cbs0)))
    #define RDB(buf, n, kk) (*(const bf16x8*)((const char*)&sm[buf][1][0]     \
        + (wn * 64 + (n) * 16 + l16) * 128 + ((kk) ? cbs1 : cbs0)))

    f32x4 acc[8][4];
#pragma unroll
    for (int m = 0; m < 8; ++m) {
#pragma unroll
        for (int n = 0; n < 4; ++n) acc[m][n] = (f32x4)0.0f;
    }

    const int NT = K >> 6;   // K-tiles of 64 (K is 512 or 1024 -> NT 8/16)

    // prologue: tile 0 fully, tile 1's (A-h0, B-h0); loop t=0 adds the rest
    STAGE(0, 0, 0, 0); STAGE(0, 0, 1, 0);
    STAGE(0, 1, 0, 0); STAGE(0, 1, 1, 0);
    STAGE(1, 1, 0, 1); STAGE(1, 0, 0, 1);
    VMCNT4();            // tile 0's 8 loads landed; tile 1's 4 may fly
    BARF();

    // one K-tile = 4 phases; each phase: ds_read subtile || stage half-tile
    // -> barrier -> lgkmcnt(0) -> setprio(1) 16xMFMA setprio(0) -> barrier.
    // vmcnt(4) only at the tile boundary (phases 2+3 stages stay in flight).
    #define TILE_STEP(t, buf, bufn) do {                                      \
        int tn1 = (t) + 1; if (tn1 == NT) tn1 = 0;                            \
        int tn2 = (t) + 2; if (tn2 >= NT) tn2 -= NT;                          \
        bf16x8 a0[4], a1[4], p0[2], p1[2], q0[2], q1[2];                      \
        /* ---- phase 0: A m0-3 + B n0-1 (12 ds_read), MFMA quad (0,0) */     \
        _Pragma("unroll") for (int m = 0; m < 4; ++m) {                       \
            a0[m] = RDA(buf, m, 0); a1[m] = RDA(buf, m, 1); }                 \
        _Pragma("unroll") for (int n = 0; n < 2; ++n) {                       \
            p0[n] = RDB(buf, n, 0); p1[n] = RDB(buf, n, 1); }                 \
        STAGE(bufn, 0, 1, tn1);                                               \
        BARF(); LGKM0();                                                      \
        __builtin_amdgcn_s_setprio(1);                                        \
        _Pragma("unroll") for (int m = 0; m < 4; ++m) {                       \
            _Pragma("unroll") for (int n = 0; n < 2; ++n) {                   \
                MFMA16(acc[m][n], a0[m], p0[n]);                              \
                MFMA16(acc[m][n], a1[m], p1[n]); } }                          \
        __builtin_amdgcn_s_setprio(0);                                        \
        BARF();                                                               \
        /* ---- phase 1: B n2-3 (4 ds_read), MFMA quad (0,1) */               \
        _Pragma("unroll") for (int n = 0; n < 2; ++n) {                       \
            q0[n] = RDB(buf, 2 + n, 0); q1[n] = RDB(buf, 2 + n, 1); }         \
        STAGE(bufn, 1, 1, tn1);                                               \
        BARF(); LGKM0();                                                      \
        __builtin_amdgcn_s_setprio(1);                                        \
        _Pragma("unroll") for (int m = 0; m < 4; ++m) {                       \
            _Pragma("unroll") for (int n = 0; n < 2; ++n) {                   \
                MFMA16(acc[m][2 + n], a0[m], q0[n]);                          \
                MFMA16(acc[m][2 + n], a1[m], q1[n]); } }                      \
        __builtin_amdgcn_s_setprio(0);                                        \
        BARF();                                                               \
        /* ---- phase 2: A m4-7 (8 ds_read), MFMA quad (1,1) */               \
        _Pragma("unroll") for (int m = 0; m < 4; ++m) {                       \
            a0[m] = RDA(buf, 4 + m, 0); a1[m] = RDA(buf, 4 + m, 1); }         \
        STAGE(buf, 1, 0, tn2);                                                \
        BARF(); LGKM0();                                                      \
        __builtin_amdgcn_s_setprio(1);                                        \
        _Pragma("unroll") for (int m = 0; m < 4; ++m) {                       \
            _Pragma("unroll") for (int n = 0; n < 2; ++n) {                   \
                MFMA16(acc[4 + m][2 + n], a0[m], q0[n]);                      \
                MFMA16(acc[4 + m][2 + n], a1[m], q1[n]); } }                  \
        __builtin_amdgcn_s_setprio(0);                                        \
        BARF();                                                               \
        /* ---- phase 3: no ds_read, MFMA quad (1,0), tile-boundary wait */   \
        STAGE(buf, 0, 0, tn2);                                                \
        BARF();                                                               \
        __builtin_amdgcn_s_setprio(1);                                        \
        _Pragma("unroll") for (int m = 0; m < 4; ++m) {                       \
            _Pragma("unroll") for (int n = 0; n < 2; ++n) {                   \
                MFMA16(acc[4 + m][n], a0[m], p0[n]);                          \
                MFMA16(acc[4 + m][n], a1[m], p1[n]); } }                      \
        __builtin_amdgcn_s_setprio(0);                                        \
        VMCNT4();   /* all of tile t+1 landed; t+2 halves stay in flight */   \
        BARF();                                                               \
    } while (0)

    for (int t = 0; t < NT; t += 2) {   // NT is even (8 or 16)
        TILE_STEP(t, 0, 1);
        TILE_STEP(t + 1, 1, 0);
    }

    // Epilogue. C/D layout: col(n)=lane&15, row(m)=quad*4+reg  [m89/m91]
#pragma unroll
    for (int m = 0; m < 8; ++m) {
        const int row0 = bM + wm * 128 + m * 16 + quad * 4;
#pragma unroll
        for (int n = 0; n < 4; ++n) {
            const int col = bN + wn * 64 + n * 16 + l16;
            float bv = 0.0f;
            if (BIASRELU) bv = bias[col];
#pragma unroll
            for (int r = 0; r < 4; ++r) {
                float val = acc[m][n][r];
                if (BIASRELU) val = fmaxf(val + bv, 0.0f);
                long long addr;
                if (SPLIT) {
                    const int bb = col >> 10;
                    const int nn = col & 1023;
                    addr = (long long)bb * splitStride
                         + (long long)(row0 + r) * 1024 + nn;
                } else {
                    addr = (long long)z * cStride
                         + (long long)(row0 + r) * N + col;
                }
                C[addr] = (short)f2bf(val);
            }
        }
    }
    #undef TILE_STEP
    #undef STAGE
    #undef RDA
    #undef RDB
}

__global__ void cvt_f32_bf16(const float4* __restrict__ in,
                             s16x4* __restrict__ out, int n4)
{
    int i = blockIdx.x * 256 + threadIdx.x;
    if (i < n4) {
        float4 v = in[i];
        s16x4 o;
        o.x = (short)f2bf(v.x); o.y = (short)f2bf(v.y);
        o.z = (short)f2bf(v.z); o.w = (short)f2bf(v.w);
        out[i] = o;
    }
}

// in[R][C] fp32 -> out[C][R] bf16, 32x32 LDS-tiled (coalesced both sides)
__global__ void transpose_cvt(const float* __restrict__ in,
                              short* __restrict__ out, int R, int C)
{
    __shared__ float tile[32][33];
    const int bc = blockIdx.x * 32;
    const int br = blockIdx.y * 32;
    const int tx = threadIdx.x & 31;
    const int ty = threadIdx.x >> 5;
#pragma unroll
    for (int i = 0; i < 32; i += 8)
        tile[ty + i][tx] = in[(long long)(br + ty + i) * C + bc + tx];
    __syncthreads();
#pragma unroll
    for (int i = 0; i < 32; i += 8)
        out[(long long)(bc + ty + i) * R + br + tx] = (short)f2bf(tile[tx][ty + i]);
}

// stage 1: partial column-sums of h2 over 128-row chunks, masked by length
__global__ void pool_partial(const short* __restrict__ h2,
                             const int* __restrict__ length,
                             float* __restrict__ part)
{
    const int b = blockIdx.y;
    const int chunk = blockIdx.x;          // 0..7
    const int t = threadIdx.x;             // 0..255, 2 channels each
    const int len = length[b];
    const int r0 = chunk * 128;
    const int r1 = min(r0 + 128, len);
    const unsigned* p = (const unsigned*)(h2 + (long long)b * 1024 * 512);
    float s0 = 0.0f, s1 = 0.0f;
    for (int r = r0; r < r1; r++) {
        unsigned v = p[r * 256 + t];
        s0 += bf2f((unsigned short)(v & 0xffffu));
        s1 += bf2f((unsigned short)(v >> 16));
    }
    float2 o; o.x = s0; o.y = s1;
    ((float2*)part)[(b * 8 + chunk) * 256 + t] = o;
}

// stage 2: sum 8 partials, dot with Wl, divide by len, add bl
__global__ void pool_final2(const float* __restrict__ part,
                            const int* __restrict__ length,
                            const float* __restrict__ Wl,
                            const float* __restrict__ bl,
                            float* __restrict__ out)
{
    const int b = blockIdx.x;
    const int t = threadIdx.x;             // 0..255
    float s0 = 0.0f, s1 = 0.0f;
#pragma unroll
    for (int c = 0; c < 8; c++) {
        float2 v = ((const float2*)part)[(b * 8 + c) * 256 + t];
        s0 += v.x; s1 += v.y;
    }
    float v = s0 * Wl[2 * t] + s1 * Wl[2 * t + 1];
#pragma unroll
    for (int off = 32; off > 0; off >>= 1) v += __shfl_down(v, off);
    __shared__ float wsum[4];
    if ((t & 63) == 0) wsum[t >> 6] = v;
    __syncthreads();
    if (t == 0) {
        float s = wsum[0] + wsum[1] + wsum[2] + wsum[3];
        out[b] = s / (float)length[b] + bl[0];
    }
}

extern "C" void kernel_launch(void* const* d_in, const int* in_sizes, int n_in,
                              void* d_out, int out_size, void* d_ws, size_t ws_size,
                              hipStream_t stream)
{
    const float* x    = (const float*)d_in[0];   // [64,1024,512]
    const float* adj  = (const float*)d_in[1];   // [64,1024,1024]
    const int*   len  = (const int*)d_in[2];     // [64]
    const float* W1   = (const float*)d_in[3];   // [512,1024]
    const float* b1   = (const float*)d_in[4];   // [1024]
    const float* W2   = (const float*)d_in[5];   // [1024,512]
    const float* b2   = (const float*)d_in[6];   // [512]
    const float* Wl   = (const float*)d_in[7];   // [512]
    const float* bl   = (const float*)d_in[8];   // [1]
    float* out = (float*)d_out;

    // workspace layout (450 MiB total)
    char* ws = (char*)d_ws;
    short* adjB  = (short*)(ws);                         // 134217728 B
    short* xS2T  = (short*)(ws + 134217728LL);           //  67108864 B (x_bf16, later S2T)
    short* W1T   = (short*)(ws + 201326592LL);           //   1048576 B
    short* W2T   = (short*)(ws + 202375168LL);           //   1048576 B
    short* S1Th2 = (short*)(ws + 203423744LL);           // 134217728 B (S1T, later h2)
    short* h1    = (short*)(ws + 337641472LL);           // 134217728 B
    float* part  = (float*)(ws + 134217728LL + 33554432LL);

    // conversions
    cvt_f32_bf16<<<65536, 256, 0, stream>>>((const float4*)adj, (s16x4*)adjB, 16777216);
    cvt_f32_bf16<<<32768, 256, 0, stream>>>((const float4*)x,   (s16x4*)xS2T,  8388608);
    transpose_cvt<<<dim3(32, 16), 256, 0, stream>>>(W1, W1T, 512, 1024);   // -> [1024,512]
    transpose_cvt<<<dim3(16, 32), 256, 0, stream>>>(W2, W2T, 1024, 512);   // -> [512,1024]

    // GEMM1 (transposed): S1T[b][h][n] = sum_f W1T[h][f] * x[b*1024+n][f]
    gemm_nt8<false, true><<<dim3(256, 4, 1), 512, 0, stream>>>(
        W1T, xS2T, S1Th2, nullptr, 1024, 65536, 512, 0, 0, 0, 1048576LL);

    // GEMM2: h1[b][i][h] = relu(sum_j adj[b][i][j] * S1T[b][h][j] + b1[h])
    gemm_nt8<true, false><<<dim3(4, 4, 64), 512, 0, stream>>>(
        adjB, S1Th2, h1, b1, 1024, 1024, 1024, 1048576LL, 1048576LL, 1048576LL, 0);

    // GEMM3 (transposed): S2T[b][h2][n] = sum_h W2T[h2][h] * h1[b*1024+n][h]
    gemm_nt8<false, true><<<dim3(256, 2, 1), 512, 0, stream>>>(
        W2T, h1, xS2T, nullptr, 512, 65536, 1024, 0, 0, 0, 524288LL);

    // GEMM4: h2[b][i][h2] = relu(sum_j adj[b][i][j] * S2T[b][h2][j] + b2[h2])
    gemm_nt8<true, false><<<dim3(2, 4, 64), 512, 0, stream>>>(
        adjB, xS2T, S1Th2, b2, 1024, 512, 1024, 1048576LL, 524288LL, 524288LL, 0);

    // pool: stage 1 (512 blocks) + stage 2 (tiny)
    pool_partial<<<dim3(8, 64), 256, 0, stream>>>(S1Th2, len, part);
    pool_final2<<<64, 256, 0, stream>>>(part, len, Wl, bl, out);
}

// Round 2
// 808.510 us; speedup vs baseline: 1.2653x; 1.1143x over previous
//
#include <hip/hip_runtime.h>
#include <hip/hip_bf16.h>
#include <stdint.h>

// ---------------------------------------------------------------------------
// GCN: h1 = relu(adj @ (x @ W1) + b1); h2 = relu(adj @ (h1 @ W2) + b2)
//      out[b] = (sum_{n<len[b]} h2[b,n,:] / len[b]) @ Wl + bl
// B=64, N=1024, NFEAT=512, NHID1=1024, NHID2=512
//
// R2: 256^2/BK=64/8-wave 8-phase GEMM template (T2 swizzle via pre-swizzled
//     global source, T3+T4 counted vmcnt, T5 setprio). 1023 -> 901 us.
// R3: (a) pool fused into GEMM4 epilogue: blocks with bM >= len[z] exit
//         early (E[37.5%] of GEMM4 work), h2 never written (saves 64MB W +
//         64MB R + pool_partial dispatch);
//     (b) XCD-aware z-swizzle on the batched adj GEMMs: XCD k owns
//         z in [8k, 8k+8) so each z's 4MB (adj+S) working set is L2-local;
//     (c) the two f32->bf16 conversion launches merged into one.
//     GEMM K-loop sync structure unchanged (verified in R2).
// ---------------------------------------------------------------------------

typedef short bf16x8 __attribute__((ext_vector_type(8)));
typedef short s16x4 __attribute__((ext_vector_type(4)));
typedef float f32x4 __attribute__((ext_vector_type(4)));

__device__ __forceinline__ unsigned short f2bf(float f) {
    union { float f; unsigned u; } v; v.f = f;
    unsigned r = v.u + 0x7fffu + ((v.u >> 16) & 1u);   // RNE
    return (unsigned short)(r >> 16);
}
__device__ __forceinline__ float bf2f(unsigned short h) {
    union { unsigned u; float f; } v; v.u = ((unsigned)h) << 16;
    return v.f;
}

typedef const __attribute__((address_space(1))) void* gp1_t;
typedef __attribute__((address_space(3))) void* lp3_t;

__device__ __forceinline__ void ldsload16(const void* g, void* l) {
    // dest = wave-uniform LDS base + lane*16 (HW semantics)
    __builtin_amdgcn_global_load_lds((gp1_t)(uintptr_t)g,
                                     (lp3_t)(unsigned)(uintptr_t)l,
                                     16, 0, 0);
}

// raw barrier + zero-cost compiler memory fence (pins LDS/VMEM ops to phases)
#define BARF()   do { __builtin_amdgcn_s_barrier(); asm volatile("" ::: "memory"); } while (0)
#define LGKM0()  asm volatile("s_waitcnt lgkmcnt(0)" ::: "memory")
#define VMCNT4() asm volatile("s_waitcnt vmcnt(4)" ::: "memory")
#define VMCNT0() asm volatile("s_waitcnt vmcnt(0)" ::: "memory")
#define MFMA16(d, a, b) d = __builtin_amdgcn_mfma_f32_16x16x32_bf16(a, b, d, 0, 0, 0)

// NT GEMM: C = A(MxK,row) * Bt(NxK,row)^T, bf16 in/out, fp32 accumulate.
// 256x256 tile, BK=64, 8 waves (2M x 4N), per-wave 128x64 output.
// SPLIT:  C index (m, nf) -> nf=b*1024+n stored at b*splitStride + m*1024 + n
// !SPLIT: C index (m, n)  -> z*cStride + m*N + n, optional bias[n] + relu
// ZSWZ:   remap blocks so XCD k (= flat%8) owns z in [k*8, k*8+8)
// POOL:   no C write; masked column-sums (rows < len[z]) -> pool_out[z][mb][512];
//         blocks with bM >= len[z] exit immediately.
template<bool BIASRELU, bool SPLIT, bool ZSWZ, bool POOL>
__global__ __launch_bounds__(512, 1)
void gemm_nt8(const short* __restrict__ A, const short* __restrict__ B,
              short* __restrict__ C, const float* __restrict__ bias,
              int M, int N, int K,
              long long aStride, long long bStride, long long cStride,
              long long splitStride,
              const int* __restrict__ length, float* __restrict__ pool_out)
{
    // [buf][A/B][256 rows][64 cols] bf16 = 128 KiB total
    __shared__ short sm[2][2][256 * 64];

    int bx, by, bz;
    if (ZSWZ) {
        const int P = gridDim.x * gridDim.y;           // blocks per z
        const int f = blockIdx.x + gridDim.x * (blockIdx.y + gridDim.y * blockIdx.z);
        const int k = f & 7;
        const int j = f >> 3;
        const int zper = gridDim.z >> 3;               // 64/8 = 8
        const int jp = j / P;
        bz = k * zper + jp;
        const int rem = j - jp * P;
        bx = rem % gridDim.x;
        by = rem / gridDim.x;
    } else {
        bx = blockIdx.x; by = blockIdx.y; bz = blockIdx.z;
    }

    const int bM = by * 256;
    const int bN = bx * 256;
    const int z  = bz;

    int len = 0;
    if (POOL) {
        len = length[z];
        if (bM >= len) return;         // dead rows: pool never reads them
    }

    const int tid  = threadIdx.x;
    const int wid  = tid >> 6;        // 0..7
    const int lane = tid & 63;
    const int wm   = wid >> 2;        // 0..1 -> 128-row half
    const int wn   = wid & 3;         // 0..3 -> 64-col quarter
    const int quad = lane >> 4;       // 0..3
    const int l16  = lane & 15;

    A += (long long)z * aStride;
    B += (long long)z * bStride;

    // --- staging addresses: thread t covers row (t>>3) of each 64-row chunk,
    //     16B at XOR-swizzled source column (rule 21: linear LDS dest,
    //     inverse-swizzled global source, swizzle applied again on ds_read)
    const int srow = tid >> 3;                                  // 0..63
    const int scbs = ((tid & 7) * 16) ^ ((srow & 7) << 4);      // swizzled col-byte
    const short* Ag = A + (long long)(bM + srow) * K + (scbs >> 1);
    const short* Bg = B + (long long)(bN + srow) * K + (scbs >> 1);
    const long long row64  = 64LL * K;
    const long long row128 = 128LL * K;

    // issue the two global_load_lds of one 128x64 half-tile (2 vmcnt events)
    #define STAGE(buf, ab, h, kt) do {                                        \
        const short* g_ = (ab ? Bg : Ag) + (h ? row128 : 0) + (kt) * 64;      \
        char* l_ = (char*)&sm[buf][ab][0] + (h) * 16384 + wid * 1024;         \
        ldsload16(g_, l_);                                                    \
        ldsload16(g_ + row64, l_ + 8192);                                     \
    } while (0)

    // swizzled ds_read column-bytes (row&7 == l16&7 for all fragment rows)
    const int cbs0 = (quad * 16) ^ ((l16 & 7) << 4);            // kk=0
    const int cbs1 = (64 + quad * 16) ^ ((l16 & 7) << 4);       // kk=1

    #define RDA(buf, m, kk) (*(const bf16x8*)((const char*)&sm[buf][0][0]     \
        + (wm * 128 + (m) * 16 + l16) * 128 + ((kk) ? cbs1 : cbs0)))
    #define RDB(buf, n, kk) (*(const bf16x8*)((const char*)&sm[buf][1][0]     \
        + (wn * 64 + (n) * 16 + l16) * 128 + ((kk) ? cbs1 : cbs0)))

    f32x4 acc[8][4];
#pragma unroll
    for (int m = 0; m < 8; ++m) {
#pragma unroll
        for (int n = 0; n < 4; ++n) acc[m][n] = (f32x4)0.0f;
    }

    const int NT = K >> 6;   // K-tiles of 64 (K is 512 or 1024 -> NT 8/16)

    // prologue: tile 0 fully, tile 1's (A-h0, B-h0); loop t=0 adds the rest
    STAGE(0, 0, 0, 0); STAGE(0, 0, 1, 0);
    STAGE(0, 1, 0, 0); STAGE(0, 1, 1, 0);
    STAGE(1, 1, 0, 1); STAGE(1, 0, 0, 1);
    VMCNT4();            // tile 0's 8 loads landed; tile 1's 4 may fly
    BARF();

    // one K-tile = 4 phases; each phase: ds_read subtile || stage half-tile
    // -> barrier -> lgkmcnt(0) -> setprio(1) 16xMFMA setprio(0) -> barrier.
    // vmcnt(4) only at the tile boundary (phases 2+3 stages stay in flight).
    #define TILE_STEP(t, buf, bufn) do {                                      \
        int tn1 = (t) + 1; if (tn1 == NT) tn1 = 0;                            \
        int tn2 = (t) + 2; if (tn2 >= NT) tn2 -= NT;                          \
        bf16x8 a0[4], a1[4], p0[2], p1[2], q0[2], q1[2];                      \
        /* ---- phase 0: A m0-3 + B n0-1 (12 ds_read), MFMA quad (0,0) */     \
        _Pragma("unroll") for (int m = 0; m < 4; ++m) {                       \
            a0[m] = RDA(buf, m, 0); a1[m] = RDA(buf, m, 1); }                 \
        _Pragma("unroll") for (int n = 0; n < 2; ++n) {                       \
            p0[n] = RDB(buf, n, 0); p1[n] = RDB(buf, n, 1); }                 \
        STAGE(bufn, 0, 1, tn1);                                               \
        BARF(); LGKM0();                                                      \
        __builtin_amdgcn_s_setprio(1);                                        \
        _Pragma("unroll") for (int m = 0; m < 4; ++m) {                       \
            _Pragma("unroll") for (int n = 0; n < 2; ++n) {                   \
                MFMA16(acc[m][n], a0[m], p0[n]);                              \
                MFMA16(acc[m][n], a1[m], p1[n]); } }                          \
        __builtin_amdgcn_s_setprio(0);                                        \
        BARF();                                                               \
        /* ---- phase 1: B n2-3 (4 ds_read), MFMA quad (0,1) */               \
        _Pragma("unroll") for (int n = 0; n < 2; ++n) {                       \
            q0[n] = RDB(buf, 2 + n, 0); q1[n] = RDB(buf, 2 + n, 1); }         \
        STAGE(bufn, 1, 1, tn1);                                               \
        BARF(); LGKM0();                                                      \
        __builtin_amdgcn_s_setprio(1);                                        \
        _Pragma("unroll") for (int m = 0; m < 4; ++m) {                       \
            _Pragma("unroll") for (int n = 0; n < 2; ++n) {                   \
                MFMA16(acc[m][2 + n], a0[m], q0[n]);                          \
                MFMA16(acc[m][2 + n], a1[m], q1[n]); } }                      \
        __builtin_amdgcn_s_setprio(0);                                        \
        BARF();                                                               \
        /* ---- phase 2: A m4-7 (8 ds_read), MFMA quad (1,1) */               \
        _Pragma("unroll") for (int m = 0; m < 4; ++m) {                       \
            a0[m] = RDA(buf, 4 + m, 0); a1[m] = RDA(buf, 4 + m, 1); }         \
        STAGE(buf, 1, 0, tn2);                                                \
        BARF(); LGKM0();                                                      \
        __builtin_amdgcn_s_setprio(1);                                        \
        _Pragma("unroll") for (int m = 0; m < 4; ++m) {                       \
            _Pragma("unroll") for (int n = 0; n < 2; ++n) {                   \
                MFMA16(acc[4 + m][2 + n], a0[m], q0[n]);                      \
                MFMA16(acc[4 + m][2 + n], a1[m], q1[n]); } }                  \
        __builtin_amdgcn_s_setprio(0);                                        \
        BARF();                                                               \
        /* ---- phase 3: no ds_read, MFMA quad (1,0), tile-boundary wait */   \
        STAGE(buf, 0, 0, tn2);                                                \
        BARF();                                                               \
        __builtin_amdgcn_s_setprio(1);                                        \
        _Pragma("unroll") for (int m = 0; m < 4; ++m) {                       \
            _Pragma("unroll") for (int n = 0; n < 2; ++n) {                   \
                MFMA16(acc[4 + m][n], a0[m], p0[n]);                          \
                MFMA16(acc[4 + m][n], a1[m], p1[n]); } }                      \
        __builtin_amdgcn_s_setprio(0);                                        \
        VMCNT4();   /* all of tile t+1 landed; t+2 halves stay in flight */   \
        BARF();                                                               \
    } while (0)

    for (int t = 0; t < NT; t += 2) {   // NT is even (8 or 16)
        TILE_STEP(t, 0, 1);
        TILE_STEP(t + 1, 1, 0);
    }

    if (POOL) {
        // fused pooling: masked column sums of the (never-materialized) C tile.
        // Drain stray tail prefetches before reusing sm as the reduce scratch.
        VMCNT0();
        __syncthreads();
        float* red = (float*)&sm[0][0][0];       // [2][256] fp32
#pragma unroll
        for (int n = 0; n < 4; ++n) {
            const int col = wn * 64 + n * 16 + l16;
            const float bv = bias[bN + col];
            float cs = 0.0f;
#pragma unroll
            for (int m = 0; m < 8; ++m) {
                const int row0 = bM + wm * 128 + m * 16 + quad * 4;
#pragma unroll
                for (int r = 0; r < 4; ++r) {
                    const float val = fmaxf(acc[m][n][r] + bv, 0.0f);
                    if (row0 + r < len) cs += val;
                }
            }
            cs += __shfl_xor(cs, 16);            // quad0<->1, quad2<->3
            cs += __shfl_xor(cs, 32);            // halves
            if (quad == 0) red[wm * 256 + col] = cs;
        }
        __syncthreads();
        if (tid < 256) {
            const float s = red[tid] + red[256 + tid];
            pool_out[((long long)z * 4 + by) * 512 + bN + tid] = s;
        }
        return;
    }

    // Epilogue. C/D layout: col(n)=lane&15, row(m)=quad*4+reg  [m89/m91]
#pragma unroll
    for (int m = 0; m < 8; ++m) {
        const int row0 = bM + wm * 128 + m * 16 + quad * 4;
#pragma unroll
        for (int n = 0; n < 4; ++n) {
            const int col = bN + wn * 64 + n * 16 + l16;
            float bv = 0.0f;
            if (BIASRELU) bv = bias[col];
#pragma unroll
            for (int r = 0; r < 4; ++r) {
                float val = acc[m][n][r];
                if (BIASRELU) val = fmaxf(val + bv, 0.0f);
                long long addr;
                if (SPLIT) {
                    const int bb = col >> 10;
                    const int nn = col & 1023;
                    addr = (long long)bb * splitStride
                         + (long long)(row0 + r) * 1024 + nn;
                } else {
                    addr = (long long)z * cStride
                         + (long long)(row0 + r) * N + col;
                }
                C[addr] = (short)f2bf(val);
            }
        }
    }
    #undef TILE_STEP
    #undef STAGE
    #undef RDA
    #undef RDB
}

// two f32->bf16 conversions in one dispatch (adj then x)
__global__ void cvt2_f32_bf16(const float4* __restrict__ inA, s16x4* __restrict__ outA, int nA4,
                              const float4* __restrict__ inB, s16x4* __restrict__ outB, int nB4)
{
    int i = blockIdx.x * 256 + threadIdx.x;
    const float4* in; s16x4* out; int j;
    if (i < nA4) { in = inA; out = outA; j = i; }
    else { j = i - nA4; if (j >= nB4) return; in = inB; out = outB; }
    float4 v = in[j];
    s16x4 o;
    o.x = (short)f2bf(v.x); o.y = (short)f2bf(v.y);
    o.z = (short)f2bf(v.z); o.w = (short)f2bf(v.w);
    out[j] = o;
}

// in[R][C] fp32 -> out[C][R] bf16, 32x32 LDS-tiled (coalesced both sides)
__global__ void transpose_cvt(const float* __restrict__ in,
                              short* __restrict__ out, int R, int C)
{
    __shared__ float tile[32][33];
    const int bc = blockIdx.x * 32;
    const int br = blockIdx.y * 32;
    const int tx = threadIdx.x & 31;
    const int ty = threadIdx.x >> 5;
#pragma unroll
    for (int i = 0; i < 32; i += 8)
        tile[ty + i][tx] = in[(long long)(br + ty + i) * C + bc + tx];
    __syncthreads();
#pragma unroll
    for (int i = 0; i < 32; i += 8)
        out[(long long)(bc + ty + i) * R + br + tx] = (short)f2bf(tile[tx][ty + i]);
}

// final pool: sum live 256-row chunks, dot with Wl, divide by len, add bl
// part layout: [b][4][512] fp32, chunk mb valid iff mb*256 < len[b]
__global__ void pool_final3(const float* __restrict__ part,
                            const int* __restrict__ length,
                            const float* __restrict__ Wl,
                            const float* __restrict__ bl,
                            float* __restrict__ out)
{
    const int b = blockIdx.x;
    const int t = threadIdx.x;             // 0..255, 2 channels each
    const int len = length[b];
    const int mbmax = (len + 255) >> 8;
    float s0 = 0.0f, s1 = 0.0f;
    for (int mb = 0; mb < mbmax; mb++) {
        float2 v = ((const float2*)part)[(b * 4 + mb) * 256 + t];
        s0 += v.x; s1 += v.y;
    }
    float v = s0 * Wl[2 * t] + s1 * Wl[2 * t + 1];
#pragma unroll
    for (int off = 32; off > 0; off >>= 1) v += __shfl_down(v, off);
    __shared__ float wsum[4];
    if ((t & 63) == 0) wsum[t >> 6] = v;
    __syncthreads();
    if (t == 0) {
        float s = wsum[0] + wsum[1] + wsum[2] + wsum[3];
        out[b] = s / (float)len + bl[0];
    }
}

extern "C" void kernel_launch(void* const* d_in, const int* in_sizes, int n_in,
                              void* d_out, int out_size, void* d_ws, size_t ws_size,
                              hipStream_t stream)
{
    const float* x    = (const float*)d_in[0];   // [64,1024,512]
    const float* adj  = (const float*)d_in[1];   // [64,1024,1024]
    const int*   len  = (const int*)d_in[2];     // [64]
    const float* W1   = (const float*)d_in[3];   // [512,1024]
    const float* b1   = (const float*)d_in[4];   // [1024]
    const float* W2   = (const float*)d_in[5];   // [1024,512]
    const float* b2   = (const float*)d_in[6];   // [512]
    const float* Wl   = (const float*)d_in[7];   // [512]
    const float* bl   = (const float*)d_in[8];   // [1]
    float* out = (float*)d_out;

    // workspace layout (450 MiB total)
    char* ws = (char*)d_ws;
    short* adjB  = (short*)(ws);                         // 134217728 B
    short* xS2T  = (short*)(ws + 134217728LL);           //  67108864 B (x_bf16, later S2T)
    short* W1T   = (short*)(ws + 201326592LL);           //   1048576 B
    short* W2T   = (short*)(ws + 202375168LL);           //   1048576 B
    short* S1T   = (short*)(ws + 203423744LL);           // 134217728 B
    short* h1    = (short*)(ws + 337641472LL);           // 134217728 B
    float* part  = (float*)(ws + 134217728LL + 33554432LL); // [64][4][512] fp32 (after S2T's 32MB)

    // conversions (adj + x in one dispatch; weight transposes)
    cvt2_f32_bf16<<<98304, 256, 0, stream>>>(
        (const float4*)adj, (s16x4*)adjB, 16777216,
        (const float4*)x,   (s16x4*)xS2T,  8388608);
    transpose_cvt<<<dim3(32, 16), 256, 0, stream>>>(W1, W1T, 512, 1024);   // -> [1024,512]
    transpose_cvt<<<dim3(16, 32), 256, 0, stream>>>(W2, W2T, 1024, 512);   // -> [512,1024]

    // GEMM1 (transposed): S1T[b][h][n] = sum_f W1T[h][f] * x[b*1024+n][f]
    gemm_nt8<false, true, false, false><<<dim3(256, 4, 1), 512, 0, stream>>>(
        W1T, xS2T, S1T, nullptr, 1024, 65536, 512, 0, 0, 0, 1048576LL, nullptr, nullptr);

    // GEMM2: h1[b][i][h] = relu(sum_j adj[b][i][j] * S1T[b][h][j] + b1[h])
    gemm_nt8<true, false, true, false><<<dim3(4, 4, 64), 512, 0, stream>>>(
        adjB, S1T, h1, b1, 1024, 1024, 1024, 1048576LL, 1048576LL, 1048576LL, 0, nullptr, nullptr);

    // GEMM3 (transposed): S2T[b][h2][n] = sum_h W2T[h2][h] * h1[b*1024+n][h]
    gemm_nt8<false, true, false, false><<<dim3(256, 2, 1), 512, 0, stream>>>(
        W2T, h1, xS2T, nullptr, 512, 65536, 1024, 0, 0, 0, 524288LL, nullptr, nullptr);

    // GEMM4 + fused pool: part[b][mb][c] = sum_{rows<len} relu(adj@S2T + b2)
    gemm_nt8<true, false, true, true><<<dim3(2, 4, 64), 512, 0, stream>>>(
        adjB, xS2T, nullptr, b2, 1024, 512, 1024, 1048576LL, 524288LL, 0, 0, len, part);

    // final pool reduction
    pool_final3<<<64, 256, 0, stream>>>(part, len, Wl, bl, out);
}